// Round 2
// baseline (483.968 us; speedup 1.0000x reference)
//
#include <hip/hip_runtime.h>
#include <cstdint>

typedef unsigned short u16;
typedef short s16x8 __attribute__((ext_vector_type(8)));
typedef float f32x4 __attribute__((ext_vector_type(4)));

__device__ __forceinline__ u16 f2bf(float x) {
  uint32_t u = __builtin_bit_cast(uint32_t, x);
  u += 0x7FFFu + ((u >> 16) & 1u);   // RTNE
  return (u16)(u >> 16);
}
__device__ __forceinline__ float bf2f(u16 v) {
  return __builtin_bit_cast(float, (uint32_t)v << 16);
}
// pack two floats -> bf16x2 (lo in bits 0-15), RTNE, v_perm merge
__device__ __forceinline__ uint32_t pk_bf16(float lo, float hi) {
  uint32_t ul = __builtin_bit_cast(uint32_t, lo);
  uint32_t uh = __builtin_bit_cast(uint32_t, hi);
  ul += 0x7FFFu + ((ul >> 16) & 1u);
  uh += 0x7FFFu + ((uh >> 16) & 1u);
  return __builtin_amdgcn_perm(uh, ul, 0x07060302u);
}
__device__ __forceinline__ f32x4 mfma16(s16x8 a, s16x8 b, f32x4 c) {
  return __builtin_amdgcn_mfma_f32_16x16x32_bf16(a, b, c, 0, 0, 0);
}
__device__ __forceinline__ s16x8 ld_frag(const u16* p) {
  uint4 v = *(const uint4*)p;
  return __builtin_bit_cast(s16x8, v);
}

// ---------------- kernel 1: weights fp32 -> bf16 (scale folded into Wq) ----
__global__ void prep_w(const float* __restrict__ Wq, const float* __restrict__ Wkv,
                       u16* __restrict__ wqb, u16* __restrict__ wkvb) {
  int i = blockIdx.x * 256 + threadIdx.x;          // grid 288*256 = 73728
  const float scale = 0.17677669529663687f;        // 1/sqrt(32)
  if (i < 36864) wqb[i] = f2bf(Wq[i] * scale);
  wkvb[i] = f2bf(Wkv[i]);
}

// ---------------- kernel 2: rpb[h][q][n] = bf16(table[rpi[q][n]][h]) -------
// n contiguous -> attention bias loads are ushort4 along keys; no transpose.
__global__ void build_rpb(const int* __restrict__ rpi, const float* __restrict__ table,
                          u16* __restrict__ rpb) {
  int q = blockIdx.x, n = threadIdx.x;             // grid 256 x block 576
  int idx = rpi[q * 576 + n] * 6;
#pragma unroll
  for (int hh = 0; hh < 6; ++hh)
    rpb[(size_t)hh * 147456 + q * 576 + n] = f2bf(table[idx + hh]);
}

// ---------------- kernels 3/4: projection GEMM (no LDS; C^T orientation) ---
// mfma(A=W-frag, B=x-frag) -> D[f][token]: lane's 4 regs = consecutive f ->
// packed dwordx2 stores. A-frags hoisted in regs (no cross-wave reuse -> no LDS).
__launch_bounds__(256, 4)
__global__ void proj_gemm(const float* __restrict__ A, const u16* __restrict__ Wb,
                          u16* __restrict__ outQ, u16* __restrict__ outK,
                          u16* __restrict__ outV, int nchunks, int mode) {
  const int t = threadIdx.x, lane = t & 63, w = t >> 6, c = lane & 15, hi = lane >> 4;
  const int mbase = (blockIdx.x << 7) + (w << 5);
  s16x8 af[2][6];                                  // x rows as B-frags, fp32->bf16
#pragma unroll
  for (int mt = 0; mt < 2; ++mt) {
    const float* ap = A + (size_t)(mbase + (mt << 4) + c) * 192;
#pragma unroll
    for (int kk = 0; kk < 6; ++kk) {
      const float4* p = (const float4*)(ap + (kk << 5) + (hi << 3));
      float4 v0 = p[0], v1 = p[1];
      uint4 q;
      q.x = pk_bf16(v0.x, v0.y); q.y = pk_bf16(v0.z, v0.w);
      q.z = pk_bf16(v1.x, v1.y); q.w = pk_bf16(v1.z, v1.w);
      af[mt][kk] = __builtin_bit_cast(s16x8, q);
    }
  }
  for (int nc = 0; nc < nchunks; ++nc) {
    f32x4 acc[2][4];
#pragma unroll
    for (int mt = 0; mt < 2; ++mt)
#pragma unroll
      for (int nb = 0; nb < 4; ++nb) acc[mt][nb] = f32x4{0.f, 0.f, 0.f, 0.f};
#pragma unroll
    for (int kk = 0; kk < 6; ++kk) {
#pragma unroll
      for (int nb = 0; nb < 4; ++nb) {
        s16x8 wf = ld_frag(&Wb[(size_t)((nc << 6) + (nb << 4) + c) * 192 + (kk << 5) + (hi << 3)]);
        acc[0][nb] = mfma16(wf, af[0][kk], acc[0][nb]);
        acc[1][nb] = mfma16(wf, af[1][kk], acc[1][nb]);
      }
    }
#pragma unroll
    for (int mt = 0; mt < 2; ++mt) {
      int m = mbase + (mt << 4) + c;
#pragma unroll
      for (int nb = 0; nb < 4; ++nb) {
        int fb = (nc << 6) + (nb << 4) + (hi << 2);
        uint2 pv;
        pv.x = pk_bf16(acc[mt][nb][0], acc[mt][nb][1]);
        pv.y = pk_bf16(acc[mt][nb][2], acc[mt][nb][3]);
        if (mode == 0) {
          int b = m >> 8, q = m & 255, hh = fb >> 5, d = fb & 31;
          *(uint2*)&outQ[((((size_t)(b * 6 + hh)) << 8) + q) * 32 + d] = pv;
        } else {
          int b = m / 576, tok = m - b * 576;
          int f2 = fb; u16* dst = outK;
          if (f2 >= 192) { dst = outV; f2 -= 192; }
          int hh = f2 >> 5, d = f2 & 31;
          *(uint2*)&dst[(((size_t)(b * 6 + hh)) * 576 + tok) * 32 + d] = pv;
        }
      }
    }
  }
}

// ---------------- kernel 5: fused attention per (b,h), S^T orientation -----
// S^T = mfma(K,Q): C-layout col = q. P^T -> PV B-frag via 8 bpermute + 4 sel
// on packed bf16 pairs (no P LDS, no lgkm drain). PV = mfma(V^T, P) -> O^T:
// regs = consecutive d -> float4 stores. Only LDS: Vt (stride 600, spread banks).
#define VSTR 600
__launch_bounds__(512, 4)
__global__ void attn(const u16* __restrict__ Qws, const u16* __restrict__ Kws,
                     const u16* __restrict__ Vws, const u16* __restrict__ rpb,
                     float* __restrict__ out) {
  __shared__ __align__(16) u16 Vt[32 * VSTR];
  const int bh = blockIdx.x, b = bh / 6, h = bh - b * 6;
  const size_t kvbase = (size_t)bh * 576 * 32;
  const int t = threadIdx.x;
  for (int i = t; i < 2304; i += 512) {            // stage V transposed [d][key]
    int key = i >> 2, dblk = i & 3;
    union { uint4 u; u16 s[8]; } v;
    v.u = *(const uint4*)(&Vws[kvbase + key * 32 + (dblk << 3)]);
#pragma unroll
    for (int j = 0; j < 8; ++j) Vt[((dblk << 3) + j) * VSTR + key] = v.s[j];
  }
  const int w = t >> 6, lane = t & 63, c = lane & 15, hi = lane >> 4;
  const int q0 = w << 5;
  s16x8 qf[2];                                     // Q as B-operand frags
#pragma unroll
  for (int qb = 0; qb < 2; ++qb)
    qf[qb] = ld_frag(&Qws[((size_t)bh * 256 + q0 + (qb << 4) + c) * 32 + (hi << 3)]);
  __syncthreads();
  f32x4 oacc[2][2];                                // [qb][db], O^T layout
  float psum[2] = {0.f, 0.f};
#pragma unroll
  for (int qb = 0; qb < 2; ++qb)
#pragma unroll
    for (int db = 0; db < 2; ++db) oacc[qb][db] = f32x4{0.f, 0.f, 0.f, 0.f};
  const u16* rpbh = rpb + (size_t)h * 147456;
  const size_t qrow0 = (size_t)(q0 + c) * 576, qrow1 = (size_t)(q0 + 16 + c) * 576;
  const int ss0 = ((hi & 1) << 5) + c, ss1 = ss0 + 16;  // bpermute src lanes
  const bool losel = hi < 2;
  // prefetch kt=0
  s16x8 kfp0 = ld_frag(&Kws[kvbase + (size_t)c * 32 + (hi << 3)]);
  s16x8 kfp1 = ld_frag(&Kws[kvbase + (size_t)(16 + c) * 32 + (hi << 3)]);
  ushort4 bp00 = *(const ushort4*)&rpbh[qrow0 + (hi << 2)];
  ushort4 bp01 = *(const ushort4*)&rpbh[qrow0 + 16 + (hi << 2)];
  ushort4 bp10 = *(const ushort4*)&rpbh[qrow1 + (hi << 2)];
  ushort4 bp11 = *(const ushort4*)&rpbh[qrow1 + 16 + (hi << 2)];
  for (int kt = 0; kt < 18; ++kt) {
    const int k0 = kt << 5;
    s16x8 kf0 = kfp0, kf1 = kfp1;
    ushort4 b00 = bp00, b01 = bp01, b10 = bp10, b11 = bp11;
    const f32x4 z = {0.f, 0.f, 0.f, 0.f};
    f32x4 st00 = mfma16(kf0, qf[0], z);            // [key16 x q16] tiles
    f32x4 st01 = mfma16(kf1, qf[0], z);
    f32x4 st10 = mfma16(kf0, qf[1], z);
    f32x4 st11 = mfma16(kf1, qf[1], z);
    if (kt < 17) {                                 // prefetch next kt
      const int kn = k0 + 32;
      kfp0 = ld_frag(&Kws[kvbase + (size_t)(kn + c) * 32 + (hi << 3)]);
      kfp1 = ld_frag(&Kws[kvbase + (size_t)(kn + 16 + c) * 32 + (hi << 3)]);
      bp00 = *(const ushort4*)&rpbh[qrow0 + kn + (hi << 2)];
      bp01 = *(const ushort4*)&rpbh[qrow0 + kn + 16 + (hi << 2)];
      bp10 = *(const ushort4*)&rpbh[qrow1 + kn + (hi << 2)];
      bp11 = *(const ushort4*)&rpbh[qrow1 + kn + 16 + (hi << 2)];
    }
    s16x8 pfr[2];
#pragma unroll
    for (int qb = 0; qb < 2; ++qb) {
      const f32x4 sa = qb ? st10 : st00, sb = qb ? st11 : st01;
      const ushort4 ba = qb ? b10 : b00, bb = qb ? b11 : b01;
      float e0 = __expf(sa[0] + bf2f(ba.x)), e1 = __expf(sa[1] + bf2f(ba.y));
      float e2 = __expf(sa[2] + bf2f(ba.z)), e3 = __expf(sa[3] + bf2f(ba.w));
      float f0 = __expf(sb[0] + bf2f(bb.x)), f1 = __expf(sb[1] + bf2f(bb.y));
      float f2 = __expf(sb[2] + bf2f(bb.z)), f3 = __expf(sb[3] + bf2f(bb.w));
      psum[qb] += ((e0 + e1) + (e2 + e3)) + ((f0 + f1) + (f2 + f3));
      uint32_t p00 = pk_bf16(e0, e1), p01 = pk_bf16(e2, e3);   // tile kb=0
      uint32_t p10 = pk_bf16(f0, f1), p11 = pk_bf16(f2, f3);   // tile kb=1
      uint32_t a0 = (uint32_t)__shfl((int)p00, ss0), g0 = (uint32_t)__shfl((int)p10, ss0);
      uint32_t a1 = (uint32_t)__shfl((int)p01, ss0), g1 = (uint32_t)__shfl((int)p11, ss0);
      uint32_t a2 = (uint32_t)__shfl((int)p00, ss1), g2 = (uint32_t)__shfl((int)p10, ss1);
      uint32_t a3 = (uint32_t)__shfl((int)p01, ss1), g3 = (uint32_t)__shfl((int)p11, ss1);
      uint4 pr;
      pr.x = losel ? a0 : g0;
      pr.y = losel ? a1 : g1;
      pr.z = losel ? a2 : g2;
      pr.w = losel ? a3 : g3;
      pfr[qb] = __builtin_bit_cast(s16x8, pr);
    }
#pragma unroll
    for (int db = 0; db < 2; ++db) {
      s16x8 vf = ld_frag(&Vt[(size_t)((db << 4) + c) * VSTR + k0 + (hi << 3)]);
      oacc[0][db] = mfma16(vf, pfr[0], oacc[0][db]);
      oacc[1][db] = mfma16(vf, pfr[1], oacc[1][db]);
    }
  }
#pragma unroll
  for (int qb = 0; qb < 2; ++qb) {                 // row-sum across hi lanes
    float v = psum[qb];
    v += __shfl_xor(v, 16);
    v += __shfl_xor(v, 32);
    float rs = 1.0f / v;
    int q = q0 + (qb << 4) + c;
    float* op = out + ((size_t)b * 256 + q) * 192 + h * 32 + (hi << 2);
#pragma unroll
    for (int db = 0; db < 2; ++db) {
      float4 o;
      o.x = oacc[qb][db][0] * rs; o.y = oacc[qb][db][1] * rs;
      o.z = oacc[qb][db][2] * rs; o.w = oacc[qb][db][3] * rs;
      *(float4*)(op + (db << 4)) = o;
    }
  }
}

// ---------------- launcher -------------------------------------------------
extern "C" void kernel_launch(void* const* d_in, const int* in_sizes, int n_in,
                              void* d_out, int out_size, void* d_ws, size_t ws_size,
                              hipStream_t stream) {
  const float* x_q   = (const float*)d_in[0];
  const float* x_kv  = (const float*)d_in[1];
  const int*   rpi   = (const int*)d_in[2];
  const float* Wq    = (const float*)d_in[3];
  const float* Wkv   = (const float*)d_in[4];
  const float* table = (const float*)d_in[5];
  float* out = (float*)d_out;

  char* ws = (char*)d_ws;
  u16* wqb  = (u16*)(ws);                          //    73,728 B
  u16* wkvb = (u16*)(ws + 73728);                  //   147,456 B
  u16* rpb  = (u16*)(ws + 221184);                 // 1,769,472 B
  u16* Qws  = (u16*)(ws + 1990656);                // 25,165,824 B
  u16* Kws  = (u16*)(ws + 27156480);               // 56,623,104 B
  u16* Vws  = (u16*)(ws + 83779584);               // 56,623,104 B  (total ~134 MB)

  prep_w<<<288, 256, 0, stream>>>(Wq, Wkv, wqb, wkvb);
  build_rpb<<<256, 576, 0, stream>>>(rpi, table, rpb);
  proj_gemm<<<512, 256, 0, stream>>>(x_q, wqb, Qws, nullptr, nullptr, 3, 0);
  proj_gemm<<<1152, 256, 0, stream>>>(x_kv, wkvb, nullptr, Kws, Vws, 6, 1);
  attn<<<1536, 512, 0, stream>>>(Qws, Kws, Vws, rpb, out);
}

// Round 3
// 446.696 us; speedup vs baseline: 1.0834x; 1.0834x over previous
//
#include <hip/hip_runtime.h>
#include <cstdint>

typedef unsigned short u16;
typedef short s16x8 __attribute__((ext_vector_type(8)));
typedef float f32x4 __attribute__((ext_vector_type(4)));

__device__ __forceinline__ u16 f2bf(float x) {
  uint32_t u = __builtin_bit_cast(uint32_t, x);
  u += 0x7FFFu + ((u >> 16) & 1u);   // RTNE
  return (u16)(u >> 16);
}
__device__ __forceinline__ float bf2f(u16 v) {
  return __builtin_bit_cast(float, (uint32_t)v << 16);
}
// pack two floats -> bf16x2 (lo in bits 0-15), RTNE, v_perm merge
__device__ __forceinline__ uint32_t pk_bf16(float lo, float hi) {
  uint32_t ul = __builtin_bit_cast(uint32_t, lo);
  uint32_t uh = __builtin_bit_cast(uint32_t, hi);
  ul += 0x7FFFu + ((ul >> 16) & 1u);
  uh += 0x7FFFu + ((uh >> 16) & 1u);
  return __builtin_amdgcn_perm(uh, ul, 0x07060302u);
}
__device__ __forceinline__ f32x4 mfma16(s16x8 a, s16x8 b, f32x4 c) {
  return __builtin_amdgcn_mfma_f32_16x16x32_bf16(a, b, c, 0, 0, 0);
}
__device__ __forceinline__ s16x8 ld_frag(const u16* p) {
  uint4 v = *(const uint4*)p;
  return __builtin_bit_cast(s16x8, v);
}

// ---------------- kernel 1: W fp32 -> bf16, MFMA-fragment-linear order -----
// Wswz[((fb*6 + kk)*64 + lane)*8 + j] = W[f=fb*16+(lane&15)][k=kk*32+(lane>>4)*8+j]
// so a W-fragment load in proj_gemm is one contiguous 1 KB wave-load.
__global__ void prep_w(const float* __restrict__ Wq, const float* __restrict__ Wkv,
                       u16* __restrict__ wqs, u16* __restrict__ wkvs) {
  int tid = blockIdx.x * 256 + threadIdx.x;        // 0 .. 13823
  if (tid >= 13824) return;
  bool isQ = tid < 4608;                           // Q: 12 fb * 6 kk * 64 lanes
  int id = isQ ? tid : tid - 4608;                 // KV: 24 fb * 6 kk * 64 lanes
  int lane = id & 63, fk = id >> 6;
  int kk = fk % 6, fb = fk / 6;
  int f = fb * 16 + (lane & 15), k0 = kk * 32 + ((lane >> 4) << 3);
  const float* src = (isQ ? Wq : Wkv) + (size_t)f * 192 + k0;
  const float sc = isQ ? 0.17677669529663687f : 1.0f;   // 1/sqrt(32) folded into Wq
  float4 a = ((const float4*)src)[0], b = ((const float4*)src)[1];
  uint4 o;
  o.x = pk_bf16(a.x * sc, a.y * sc); o.y = pk_bf16(a.z * sc, a.w * sc);
  o.z = pk_bf16(b.x * sc, b.y * sc); o.w = pk_bf16(b.z * sc, b.w * sc);
  *(uint4*)&(isQ ? wqs : wkvs)[(size_t)id * 8] = o;
}

// ---------------- kernel 2: rpb[h][q][n] = bf16(table[rpi[q][n]][h]) -------
__global__ void build_rpb(const int* __restrict__ rpi, const float* __restrict__ table,
                          u16* __restrict__ rpb) {
  int q = blockIdx.x, n = threadIdx.x;             // grid 256 x block 576
  int idx = rpi[q * 576 + n] * 6;
#pragma unroll
  for (int hh = 0; hh < 6; ++hh)
    rpb[(size_t)hh * 147456 + q * 576 + n] = f2bf(table[idx + hh]);
}

// ---------------- kernels 3/4: projection GEMM (swizzled W, C^T orient) ----
// mfma(A=W-frag, B=x-frag) -> D[f][token]; W-frags are contiguous 1 KB
// wave-loads from the swizzled layout; x-frags hoisted in registers.
__launch_bounds__(256, 4)
__global__ void proj_gemm(const float* __restrict__ A, const u16* __restrict__ Wswz,
                          u16* __restrict__ outQ, u16* __restrict__ outK,
                          u16* __restrict__ outV, int nchunks, int mode) {
  const int t = threadIdx.x, lane = t & 63, w = t >> 6, c = lane & 15, hi = lane >> 4;
  const int mbase = (blockIdx.x << 7) + (w << 5);
  s16x8 af[2][6];                                  // x rows as B-frags, fp32->bf16
#pragma unroll
  for (int mt = 0; mt < 2; ++mt) {
    const float* ap = A + (size_t)(mbase + (mt << 4) + c) * 192;
#pragma unroll
    for (int kk = 0; kk < 6; ++kk) {
      const float4* p = (const float4*)(ap + (kk << 5) + (hi << 3));
      float4 v0 = p[0], v1 = p[1];
      uint4 q;
      q.x = pk_bf16(v0.x, v0.y); q.y = pk_bf16(v0.z, v0.w);
      q.z = pk_bf16(v1.x, v1.y); q.w = pk_bf16(v1.z, v1.w);
      af[mt][kk] = __builtin_bit_cast(s16x8, q);
    }
  }
  for (int nc = 0; nc < nchunks; ++nc) {
    f32x4 acc[2][4];
#pragma unroll
    for (int mt = 0; mt < 2; ++mt)
#pragma unroll
      for (int nb = 0; nb < 4; ++nb) acc[mt][nb] = f32x4{0.f, 0.f, 0.f, 0.f};
#pragma unroll
    for (int kk = 0; kk < 6; ++kk) {
#pragma unroll
      for (int nb = 0; nb < 4; ++nb) {
        int fb = (nc << 2) + nb;                   // 16-feature block id
        s16x8 wf = ld_frag(&Wswz[(((size_t)(fb * 6 + kk) << 6) + lane) << 3]);
        acc[0][nb] = mfma16(wf, af[0][kk], acc[0][nb]);
        acc[1][nb] = mfma16(wf, af[1][kk], acc[1][nb]);
      }
    }
#pragma unroll
    for (int mt = 0; mt < 2; ++mt) {
      int m = mbase + (mt << 4) + c;
#pragma unroll
      for (int nb = 0; nb < 4; ++nb) {
        int fb = (nc << 6) + (nb << 4) + (hi << 2);
        uint2 pv;
        pv.x = pk_bf16(acc[mt][nb][0], acc[mt][nb][1]);
        pv.y = pk_bf16(acc[mt][nb][2], acc[mt][nb][3]);
        if (mode == 0) {
          int b = m >> 8, q = m & 255, hh = fb >> 5, d = fb & 31;
          *(uint2*)&outQ[((((size_t)(b * 6 + hh)) << 8) + q) * 32 + d] = pv;
        } else {
          int b = m / 576, tok = m - b * 576;
          int f2 = fb; u16* dst = outK;
          if (f2 >= 192) { dst = outV; f2 -= 192; }
          int hh = f2 >> 5, d = f2 & 31;
          *(uint2*)&dst[(((size_t)(b * 6 + hh)) * 576 + tok) * 32 + d] = pv;
        }
      }
    }
  }
}

// ---------------- kernel 5: fused attention per (b,h), S^T orientation -----
#define VSTR 600
__launch_bounds__(512, 4)
__global__ void attn(const u16* __restrict__ Qws, const u16* __restrict__ Kws,
                     const u16* __restrict__ Vws, const u16* __restrict__ rpb,
                     float* __restrict__ out) {
  __shared__ __align__(16) u16 Vt[32 * VSTR];
  const int bh = blockIdx.x, b = bh / 6, h = bh - b * 6;
  const size_t kvbase = (size_t)bh * 576 * 32;
  const int t = threadIdx.x;
  for (int i = t; i < 2304; i += 512) {            // stage V transposed [d][key]
    int key = i >> 2, dblk = i & 3;
    union { uint4 u; u16 s[8]; } v;
    v.u = *(const uint4*)(&Vws[kvbase + key * 32 + (dblk << 3)]);
#pragma unroll
    for (int j = 0; j < 8; ++j) Vt[((dblk << 3) + j) * VSTR + key] = v.s[j];
  }
  const int w = t >> 6, lane = t & 63, c = lane & 15, hi = lane >> 4;
  const int q0 = w << 5;
  s16x8 qf[2];                                     // Q as B-operand frags
#pragma unroll
  for (int qb = 0; qb < 2; ++qb)
    qf[qb] = ld_frag(&Qws[((size_t)bh * 256 + q0 + (qb << 4) + c) * 32 + (hi << 3)]);
  __syncthreads();
  f32x4 oacc[2][2];                                // [qb][db], O^T layout
  float psum[2] = {0.f, 0.f};
#pragma unroll
  for (int qb = 0; qb < 2; ++qb)
#pragma unroll
    for (int db = 0; db < 2; ++db) oacc[qb][db] = f32x4{0.f, 0.f, 0.f, 0.f};
  const u16* rpbh = rpb + (size_t)h * 147456;
  const size_t qrow0 = (size_t)(q0 + c) * 576, qrow1 = (size_t)(q0 + 16 + c) * 576;
  const int ss0 = ((hi & 1) << 5) + c, ss1 = ss0 + 16;  // bpermute src lanes
  const bool losel = hi < 2;
  // prefetch kt=0
  s16x8 kfp0 = ld_frag(&Kws[kvbase + (size_t)c * 32 + (hi << 3)]);
  s16x8 kfp1 = ld_frag(&Kws[kvbase + (size_t)(16 + c) * 32 + (hi << 3)]);
  ushort4 bp00 = *(const ushort4*)&rpbh[qrow0 + (hi << 2)];
  ushort4 bp01 = *(const ushort4*)&rpbh[qrow0 + 16 + (hi << 2)];
  ushort4 bp10 = *(const ushort4*)&rpbh[qrow1 + (hi << 2)];
  ushort4 bp11 = *(const ushort4*)&rpbh[qrow1 + 16 + (hi << 2)];
  for (int kt = 0; kt < 18; ++kt) {
    const int k0 = kt << 5;
    s16x8 kf0 = kfp0, kf1 = kfp1;
    ushort4 b00 = bp00, b01 = bp01, b10 = bp10, b11 = bp11;
    const f32x4 z = {0.f, 0.f, 0.f, 0.f};
    f32x4 st00 = mfma16(kf0, qf[0], z);            // [key16 x q16] tiles
    f32x4 st01 = mfma16(kf1, qf[0], z);
    f32x4 st10 = mfma16(kf0, qf[1], z);
    f32x4 st11 = mfma16(kf1, qf[1], z);
    if (kt < 17) {                                 // prefetch next kt
      const int kn = k0 + 32;
      kfp0 = ld_frag(&Kws[kvbase + (size_t)(kn + c) * 32 + (hi << 3)]);
      kfp1 = ld_frag(&Kws[kvbase + (size_t)(kn + 16 + c) * 32 + (hi << 3)]);
      bp00 = *(const ushort4*)&rpbh[qrow0 + kn + (hi << 2)];
      bp01 = *(const ushort4*)&rpbh[qrow0 + kn + 16 + (hi << 2)];
      bp10 = *(const ushort4*)&rpbh[qrow1 + kn + (hi << 2)];
      bp11 = *(const ushort4*)&rpbh[qrow1 + kn + 16 + (hi << 2)];
    }
    s16x8 pfr[2];
#pragma unroll
    for (int qb = 0; qb < 2; ++qb) {
      const f32x4 sa = qb ? st10 : st00, sb = qb ? st11 : st01;
      const ushort4 ba = qb ? b10 : b00, bb = qb ? b11 : b01;
      float e0 = __expf(sa[0] + bf2f(ba.x)), e1 = __expf(sa[1] + bf2f(ba.y));
      float e2 = __expf(sa[2] + bf2f(ba.z)), e3 = __expf(sa[3] + bf2f(ba.w));
      float f0 = __expf(sb[0] + bf2f(bb.x)), f1 = __expf(sb[1] + bf2f(bb.y));
      float f2 = __expf(sb[2] + bf2f(bb.z)), f3 = __expf(sb[3] + bf2f(bb.w));
      psum[qb] += ((e0 + e1) + (e2 + e3)) + ((f0 + f1) + (f2 + f3));
      uint32_t p00 = pk_bf16(e0, e1), p01 = pk_bf16(e2, e3);   // tile kb=0
      uint32_t p10 = pk_bf16(f0, f1), p11 = pk_bf16(f2, f3);   // tile kb=1
      uint32_t a0 = (uint32_t)__shfl((int)p00, ss0), g0 = (uint32_t)__shfl((int)p10, ss0);
      uint32_t a1 = (uint32_t)__shfl((int)p01, ss0), g1 = (uint32_t)__shfl((int)p11, ss0);
      uint32_t a2 = (uint32_t)__shfl((int)p00, ss1), g2 = (uint32_t)__shfl((int)p10, ss1);
      uint32_t a3 = (uint32_t)__shfl((int)p01, ss1), g3 = (uint32_t)__shfl((int)p11, ss1);
      uint4 pr;
      pr.x = losel ? a0 : g0;
      pr.y = losel ? a1 : g1;
      pr.z = losel ? a2 : g2;
      pr.w = losel ? a3 : g3;
      pfr[qb] = __builtin_bit_cast(s16x8, pr);
    }
#pragma unroll
    for (int db = 0; db < 2; ++db) {
      s16x8 vf = ld_frag(&Vt[(size_t)((db << 4) + c) * VSTR + k0 + (hi << 3)]);
      oacc[0][db] = mfma16(vf, pfr[0], oacc[0][db]);
      oacc[1][db] = mfma16(vf, pfr[1], oacc[1][db]);
    }
  }
#pragma unroll
  for (int qb = 0; qb < 2; ++qb) {                 // row-sum across hi lanes
    float v = psum[qb];
    v += __shfl_xor(v, 16);
    v += __shfl_xor(v, 32);
    float rs = 1.0f / v;
    int q = q0 + (qb << 4) + c;
    float* op = out + ((size_t)b * 256 + q) * 192 + h * 32 + (hi << 2);
#pragma unroll
    for (int db = 0; db < 2; ++db) {
      float4 o;
      o.x = oacc[qb][db][0] * rs; o.y = oacc[qb][db][1] * rs;
      o.z = oacc[qb][db][2] * rs; o.w = oacc[qb][db][3] * rs;
      *(float4*)(op + (db << 4)) = o;
    }
  }
}

// ---------------- launcher -------------------------------------------------
extern "C" void kernel_launch(void* const* d_in, const int* in_sizes, int n_in,
                              void* d_out, int out_size, void* d_ws, size_t ws_size,
                              hipStream_t stream) {
  const float* x_q   = (const float*)d_in[0];
  const float* x_kv  = (const float*)d_in[1];
  const int*   rpi   = (const int*)d_in[2];
  const float* Wq    = (const float*)d_in[3];
  const float* Wkv   = (const float*)d_in[4];
  const float* table = (const float*)d_in[5];
  float* out = (float*)d_out;

  char* ws = (char*)d_ws;
  u16* wqs  = (u16*)(ws);                          //    73,728 B (swizzled)
  u16* wkvs = (u16*)(ws + 73728);                  //   147,456 B (swizzled)
  u16* rpb  = (u16*)(ws + 221184);                 // 1,769,472 B
  u16* Qws  = (u16*)(ws + 1990656);                // 25,165,824 B
  u16* Kws  = (u16*)(ws + 27156480);               // 56,623,104 B
  u16* Vws  = (u16*)(ws + 83779584);               // 56,623,104 B  (total ~134 MB)

  prep_w<<<54, 256, 0, stream>>>(Wq, Wkv, wqs, wkvs);
  build_rpb<<<256, 576, 0, stream>>>(rpi, table, rpb);
  proj_gemm<<<512, 256, 0, stream>>>(x_q, wqs, Qws, nullptr, nullptr, 3, 0);
  proj_gemm<<<1152, 256, 0, stream>>>(x_kv, wkvs, nullptr, Kws, Vws, 6, 1);
  attn<<<1536, 512, 0, stream>>>(Qws, Kws, Vws, rpb, out);
}